// Round 2
// baseline (79.926 us; speedup 1.0000x reference)
//
#include <hip/hip_runtime.h>
#include <math.h>

constexpr int BATCH = 4;
constexpr int NPTS  = 8192;
constexpr int BLOCK = 256;
constexpr int P     = 8;                            // own points per thread
constexpr int OWN_TILE   = BLOCK * P;               // 2048
constexpr int OTHER_TILE = 512;                     // other-cloud chunk in LDS
constexpr int GROUPS = NPTS / OWN_TILE;             // 4
constexpr int CHUNKS = NPTS / OTHER_TILE;           // 16
constexpr int BLOCKS_PER_DIR = BATCH * GROUPS * CHUNKS; // 256
constexpr int CLOUD = BATCH * NPTS;                 // 32768

// ---------------------------------------------------------------- init: +inf
__global__ void cd_init(unsigned int* __restrict__ w, int n) {
    int i = blockIdx.x * blockDim.x + threadIdx.x;
    if (i < n) w[i] = 0x7F800000u;
}

// ------------------------------------------------- main: per-chunk min pass
__global__ __launch_bounds__(BLOCK) void cd_min(
    const float* __restrict__ xyz1, const float* __restrict__ xyz2,
    unsigned int* __restrict__ dmin /* [2 * CLOUD] */) {

    const int bid = blockIdx.x;
    const int dir = bid >> 8;        // BLOCKS_PER_DIR == 256
    const int lb  = bid & 255;
    const int b   = lb >> 6;         // batch (4)   : GROUPS*CHUNKS = 64
    const int rem = lb & 63;
    const int grp = rem >> 4;        // own group (4)
    const int chk = rem & 15;        // other chunk (16)

    const float* own = dir ? xyz2 : xyz1;
    const float* oth = dir ? xyz1 : xyz2;
    unsigned int* dptr = dmin + dir * CLOUD;

    const int ownBase = b * NPTS + grp * OWN_TILE;
    const int othBase = b * NPTS + chk * OTHER_TILE;

    __shared__ float4 tile[OTHER_TILE + 2];   // (x,y,z,|p|^2) — 8 KB + pad

    const int t = threadIdx.x;

    // ---- stage other chunk: threads 0..127 handle 4 consecutive points each
    if (t < OTHER_TILE / 4) {
        const float4* src =
            reinterpret_cast<const float4*>(oth + (size_t)othBase * 3) + t * 3;
        float4 a = src[0], q = src[1], c = src[2];
        tile[t * 4 + 0] = make_float4(a.x, a.y, a.z, a.x*a.x + a.y*a.y + a.z*a.z);
        tile[t * 4 + 1] = make_float4(a.w, q.x, q.y, a.w*a.w + q.x*q.x + q.y*q.y);
        tile[t * 4 + 2] = make_float4(q.z, q.w, c.x, q.z*q.z + q.w*q.w + c.x*c.x);
        tile[t * 4 + 3] = make_float4(c.y, c.z, c.w, c.y*c.y + c.z*c.z + c.w*c.w);
    } else if (t == OTHER_TILE / 4) {
        tile[OTHER_TILE]     = make_float4(0.f, 0.f, 0.f, 0.f);  // prefetch pad
        tile[OTHER_TILE + 1] = make_float4(0.f, 0.f, 0.f, 0.f);
    }

    // ---- own points: 8 per thread, consecutive (6 float4 = 24 floats)
    float nx[P], ny[P], nz[P], rr[P], mv[P];
    {
        const float4* src =
            reinterpret_cast<const float4*>(own + (size_t)ownBase * 3) + t * 6;
        float4 A = src[0], Bv = src[1], C = src[2],
               D = src[3], E  = src[4], F = src[5];
        const float f[24] = {A.x, A.y, A.z, A.w,  Bv.x, Bv.y, Bv.z, Bv.w,
                             C.x, C.y, C.z, C.w,  D.x,  D.y,  D.z,  D.w,
                             E.x, E.y, E.z, E.w,  F.x,  F.y,  F.z,  F.w};
#pragma unroll
        for (int p = 0; p < P; ++p) {
            const float px = f[3*p], py = f[3*p+1], pz = f[3*p+2];
            nx[p] = -2.0f * px;
            ny[p] = -2.0f * py;
            nz[p] = -2.0f * pz;
            rr[p] = px*px + py*py + pz*pz;
            mv[p] = INFINITY;
        }
    }
    __syncthreads();

    // ---- scan chunk: 2 other-points per step, register-prefetched.
    // Per pair: 3 FMA; two pairs share one v_min3 -> 3.5 VALU ops / pair.
    float4 qa = tile[0], qb = tile[1];
    for (int j = 0; j < OTHER_TILE; j += 2) {
        float4 qc = tile[j + 2];   // prefetch (pad covers final iteration)
        float4 qd = tile[j + 3];
#pragma unroll
        for (int p = 0; p < P; ++p) {
            float va = fmaf(nx[p], qa.x, qa.w);
            va = fmaf(ny[p], qa.y, va);
            va = fmaf(nz[p], qa.z, va);
            float vb = fmaf(nx[p], qb.x, qb.w);
            vb = fmaf(ny[p], qb.y, vb);
            vb = fmaf(nz[p], qb.z, vb);
            mv[p] = fminf(mv[p], fminf(va, vb));   // -> v_min3_f32
        }
        qa = qc; qb = qd;
    }

    // ---- publish: d = max(r1 + min, 0); uint atomicMin exact for d >= 0
#pragma unroll
    for (int p = 0; p < P; ++p) {
        float d = fmaxf(rr[p] + mv[p], 0.0f);
        atomicMin(&dptr[ownBase + t * P + p], __float_as_uint(d));
    }
}

// ------------------------------------------ final: deterministic sum + means
__global__ __launch_bounds__(1024) void cd_reduce(
    const unsigned int* __restrict__ dmin, float* __restrict__ out) {
    __shared__ float s1[16], s2[16];
    const int t = threadIdx.x;
    float a = 0.0f, c = 0.0f;
    for (int i = t; i < CLOUD; i += 1024) {
        a += __uint_as_float(dmin[i]);
        c += __uint_as_float(dmin[CLOUD + i]);
    }
#pragma unroll
    for (int off = 32; off > 0; off >>= 1) {
        a += __shfl_down(a, off, 64);
        c += __shfl_down(c, off, 64);
    }
    const int wave = t >> 6;
    if ((t & 63) == 0) { s1[wave] = a; s2[wave] = c; }
    __syncthreads();
    if (t == 0) {
        float ta = 0.0f, tc = 0.0f;
#pragma unroll
        for (int w = 0; w < 16; ++w) { ta += s1[w]; tc += s2[w]; }
        out[0] = ta / (float)CLOUD + tc / (float)CLOUD;
    }
}

extern "C" void kernel_launch(void* const* d_in, const int* in_sizes, int n_in,
                              void* d_out, int out_size, void* d_ws, size_t ws_size,
                              hipStream_t stream) {
    const float* xyz1 = (const float*)d_in[0];
    const float* xyz2 = (const float*)d_in[1];
    unsigned int* dmin = (unsigned int*)d_ws;   // 2 * 32768 uints = 256 KB
    float* out = (float*)d_out;

    cd_init<<<(2 * CLOUD + 255) / 256, 256, 0, stream>>>(dmin, 2 * CLOUD);
    cd_min<<<2 * BLOCKS_PER_DIR, BLOCK, 0, stream>>>(xyz1, xyz2, dmin);
    cd_reduce<<<1, 1024, 0, stream>>>(dmin, out);
}

// Round 3
// 61.641 us; speedup vs baseline: 1.2966x; 1.2966x over previous
//
#include <hip/hip_runtime.h>
#include <math.h>

constexpr int BATCH = 4;
constexpr int NPTS  = 8192;
constexpr int BLOCK = 256;
constexpr int P     = 4;                            // own points per thread
constexpr int OWN_TILE   = BLOCK * P;               // 1024
constexpr int OTHER_TILE = 512;                     // other-cloud chunk in LDS
constexpr int GROUPS = NPTS / OWN_TILE;             // 8
constexpr int CHUNKS = NPTS / OTHER_TILE;           // 16
constexpr int BLOCKS_PER_DIR = BATCH * GROUPS * CHUNKS; // 512
constexpr int CLOUD = BATCH * NPTS;                 // 32768

// ---------------------------------------------------------------- init: +inf
__global__ void cd_init(unsigned int* __restrict__ w, int n) {
    int i = blockIdx.x * blockDim.x + threadIdx.x;
    if (i < n) w[i] = 0x7F800000u;
}

// ------------------------------------------------- main: per-chunk min pass
__global__ __launch_bounds__(BLOCK, 4) void cd_min(
    const float* __restrict__ xyz1, const float* __restrict__ xyz2,
    unsigned int* __restrict__ dmin /* [2 * CLOUD] */) {

    const int bid = blockIdx.x;
    const int dir = bid >> 9;        // BLOCKS_PER_DIR == 512
    const int lb  = bid & 511;
    const int b   = lb >> 7;         // batch (4): GROUPS*CHUNKS = 128
    const int rem = lb & 127;
    const int grp = rem >> 4;        // own group (8)
    const int chk = rem & 15;        // other chunk (16)

    const float* own = dir ? xyz2 : xyz1;
    const float* oth = dir ? xyz1 : xyz2;
    unsigned int* dptr = dmin + dir * CLOUD;

    const int ownBase = b * NPTS + grp * OWN_TILE;
    const int othBase = b * NPTS + chk * OTHER_TILE;

    __shared__ float4 tile[OTHER_TILE + 4];   // (x,y,z,|p|^2) — 8 KB + pad

    const int t = threadIdx.x;

    // ---- stage other chunk: threads 0..127 handle 4 consecutive points each
    if (t < OTHER_TILE / 4) {
        const float4* src =
            reinterpret_cast<const float4*>(oth + (size_t)othBase * 3) + t * 3;
        float4 a = src[0], q = src[1], c = src[2];
        tile[t * 4 + 0] = make_float4(a.x, a.y, a.z, a.x*a.x + a.y*a.y + a.z*a.z);
        tile[t * 4 + 1] = make_float4(a.w, q.x, q.y, a.w*a.w + q.x*q.x + q.y*q.y);
        tile[t * 4 + 2] = make_float4(q.z, q.w, c.x, q.z*q.z + q.w*q.w + c.x*c.x);
        tile[t * 4 + 3] = make_float4(c.y, c.z, c.w, c.y*c.y + c.z*c.z + c.w*c.w);
    } else if (t == OTHER_TILE / 4) {
        tile[OTHER_TILE + 0] = make_float4(0.f, 0.f, 0.f, 0.f);  // prefetch pad
        tile[OTHER_TILE + 1] = make_float4(0.f, 0.f, 0.f, 0.f);
        tile[OTHER_TILE + 2] = make_float4(0.f, 0.f, 0.f, 0.f);
        tile[OTHER_TILE + 3] = make_float4(0.f, 0.f, 0.f, 0.f);
    }

    // ---- own points: 4 per thread, consecutive (3 float4 = 12 floats)
    float nx0, ny0, nz0, nx1, ny1, nz1, nx2, ny2, nz2, nx3, ny3, nz3;
    float rr[P];
    {
        const float4* src =
            reinterpret_cast<const float4*>(own + (size_t)ownBase * 3) + t * 3;
        float4 a = src[0], q = src[1], c = src[2];
        nx0 = -2.0f*a.x; ny0 = -2.0f*a.y; nz0 = -2.0f*a.z;
        nx1 = -2.0f*a.w; ny1 = -2.0f*q.x; nz1 = -2.0f*q.y;
        nx2 = -2.0f*q.z; ny2 = -2.0f*q.w; nz2 = -2.0f*c.x;
        nx3 = -2.0f*c.y; ny3 = -2.0f*c.z; nz3 = -2.0f*c.w;
        rr[0] = a.x*a.x + a.y*a.y + a.z*a.z;
        rr[1] = a.w*a.w + q.x*q.x + q.y*q.y;
        rr[2] = q.z*q.z + q.w*q.w + c.x*c.x;
        rr[3] = c.y*c.y + c.z*c.z + c.w*c.w;
    }
    float ma0 = INFINITY, ma1 = INFINITY, ma2 = INFINITY, ma3 = INFINITY;
    float mb0 = INFINITY, mb1 = INFINITY, mb2 = INFINITY, mb3 = INFINITY;
    __syncthreads();

    // ---- scan chunk: 4 other-points per step, register-prefetched.
    // Per own point per step: 12 FMA + 2 min3 = 3.5 VALU/pair.
    float4 q0 = tile[0], q1 = tile[1], q2 = tile[2], q3 = tile[3];
    for (int j = 0; j < OTHER_TILE; j += 4) {
        float4 p0 = tile[j + 4];   // pad covers the final iteration
        float4 p1 = tile[j + 5];
        float4 p2 = tile[j + 6];
        float4 p3 = tile[j + 7];

#define CD_DIST(q, NX, NY, NZ) \
    fmaf(NZ, q.z, fmaf(NY, q.y, fmaf(NX, q.x, q.w)))

        {
            float v0 = CD_DIST(q0, nx0, ny0, nz0);
            float v1 = CD_DIST(q1, nx0, ny0, nz0);
            float v2 = CD_DIST(q2, nx0, ny0, nz0);
            float v3 = CD_DIST(q3, nx0, ny0, nz0);
            ma0 = fminf(fminf(v0, v1), ma0);
            mb0 = fminf(fminf(v2, v3), mb0);
        }
        {
            float v0 = CD_DIST(q0, nx1, ny1, nz1);
            float v1 = CD_DIST(q1, nx1, ny1, nz1);
            float v2 = CD_DIST(q2, nx1, ny1, nz1);
            float v3 = CD_DIST(q3, nx1, ny1, nz1);
            ma1 = fminf(fminf(v0, v1), ma1);
            mb1 = fminf(fminf(v2, v3), mb1);
        }
        {
            float v0 = CD_DIST(q0, nx2, ny2, nz2);
            float v1 = CD_DIST(q1, nx2, ny2, nz2);
            float v2 = CD_DIST(q2, nx2, ny2, nz2);
            float v3 = CD_DIST(q3, nx2, ny2, nz2);
            ma2 = fminf(fminf(v0, v1), ma2);
            mb2 = fminf(fminf(v2, v3), mb2);
        }
        {
            float v0 = CD_DIST(q0, nx3, ny3, nz3);
            float v1 = CD_DIST(q1, nx3, ny3, nz3);
            float v2 = CD_DIST(q2, nx3, ny3, nz3);
            float v3 = CD_DIST(q3, nx3, ny3, nz3);
            ma3 = fminf(fminf(v0, v1), ma3);
            mb3 = fminf(fminf(v2, v3), mb3);
        }
#undef CD_DIST
        q0 = p0; q1 = p1; q2 = p2; q3 = p3;
    }

    // ---- publish: d = max(r1 + min, 0); uint atomicMin exact for d >= 0
    const float mv[P] = {fminf(ma0, mb0), fminf(ma1, mb1),
                         fminf(ma2, mb2), fminf(ma3, mb3)};
#pragma unroll
    for (int p = 0; p < P; ++p) {
        float d = fmaxf(rr[p] + mv[p], 0.0f);
        atomicMin(&dptr[ownBase + t * P + p], __float_as_uint(d));
    }
}

// ------------------------------------------ final: deterministic sum + means
__global__ __launch_bounds__(1024) void cd_reduce(
    const unsigned int* __restrict__ dmin, float* __restrict__ out) {
    __shared__ float s1[16], s2[16];
    const int t = threadIdx.x;
    float a = 0.0f, c = 0.0f;
    for (int i = t; i < CLOUD; i += 1024) {
        a += __uint_as_float(dmin[i]);
        c += __uint_as_float(dmin[CLOUD + i]);
    }
#pragma unroll
    for (int off = 32; off > 0; off >>= 1) {
        a += __shfl_down(a, off, 64);
        c += __shfl_down(c, off, 64);
    }
    const int wave = t >> 6;
    if ((t & 63) == 0) { s1[wave] = a; s2[wave] = c; }
    __syncthreads();
    if (t == 0) {
        float ta = 0.0f, tc = 0.0f;
#pragma unroll
        for (int w = 0; w < 16; ++w) { ta += s1[w]; tc += s2[w]; }
        out[0] = ta / (float)CLOUD + tc / (float)CLOUD;
    }
}

extern "C" void kernel_launch(void* const* d_in, const int* in_sizes, int n_in,
                              void* d_out, int out_size, void* d_ws, size_t ws_size,
                              hipStream_t stream) {
    const float* xyz1 = (const float*)d_in[0];
    const float* xyz2 = (const float*)d_in[1];
    unsigned int* dmin = (unsigned int*)d_ws;   // 2 * 32768 uints = 256 KB
    float* out = (float*)d_out;

    cd_init<<<(2 * CLOUD + 255) / 256, 256, 0, stream>>>(dmin, 2 * CLOUD);
    cd_min<<<2 * BLOCKS_PER_DIR, BLOCK, 0, stream>>>(xyz1, xyz2, dmin);
    cd_reduce<<<1, 1024, 0, stream>>>(dmin, out);
}